// Round 1
// baseline (1382.296 us; speedup 1.0000x reference)
//
#include <hip/hip_runtime.h>

// Swin shifted-window attention, fused single kernel.
// B=4, C=192, H=W=256, ws=8, shift=4, heads=8, hd=24, N=64 tokens/window.
// 1 block = 1 window. 256 threads = 4 waves.
//
// All GEMMs computed transposed: D[o][t] = W(o,k) @ X^T(k,t) so both A and B
// fragments are contiguous 8-bf16 loads, and proj output is token-minor
// (coalesced global stores).
//
// MFMA 16x16x32 bf16 layouts (learn_hip-verified):
//   A-frag: lane holds A[m=lane&15][k=(lane>>4)*8 + j], j=0..7
//   B-frag: lane holds B[k=(lane>>4)*8 + j][n=lane&15]
//   C/D   : lane holds D[row=(lane>>4)*4 + r][col=lane&15], r=0..3

typedef short short8 __attribute__((ext_vector_type(8)));
typedef float f32x4 __attribute__((ext_vector_type(4)));

// LDS layout (offsets in 16-bit units unless noted)
#define QS_OFF   0        // [64][200] bf16  token-major Q (8 heads x 24 packed)
#define KS_OFF   12800    // [64][200] bf16  token-major K
#define VT_OFF   25600    // [200][72] bf16  channel-major V (rows 192..199 slack)
#define SCR_OFF  40000    // phase1: Xbf [64][200]; phase2: P per-wave [4][64][72]
#define OS_OFF   58432    // [64][200] bf16  attention output O token-major
#define RPB_BYTE 142464   // float [8][228]  rpb transposed head-major
#define LDS_BYTES 149760

__device__ __forceinline__ unsigned short f2bfu(float f) {
  union { float f; unsigned u; } v; v.f = f;
  unsigned u = v.u;
  u += 0x7fffu + ((u >> 16) & 1u);   // round-to-nearest-even
  return (unsigned short)(u >> 16);
}

__global__ __launch_bounds__(256) void winattn_kernel(
    const float* __restrict__ x, const float* __restrict__ qkv_w,
    const float* __restrict__ qkv_b, const float* __restrict__ proj_w,
    const float* __restrict__ proj_b, const float* __restrict__ rpb,
    float* __restrict__ out)
{
  extern __shared__ __align__(16) char smem[];
  unsigned short* lds = (unsigned short*)smem;
  unsigned short* Qs = lds + QS_OFF;
  unsigned short* Ks = lds + KS_OFF;
  unsigned short* Vt = lds + VT_OFF;
  unsigned short* Xb = lds + SCR_OFF;
  unsigned short* Os = lds + OS_OFF;
  float* RPB = (float*)(smem + RPB_BYTE);

  const int tid  = threadIdx.x;
  const int lane = tid & 63;
  const int wave = tid >> 6;
  const int n16  = lane & 15;
  const int q4   = lane >> 4;

  const int blk  = blockIdx.x;
  const int b    = blk >> 10;      // batch
  const int wIdx = blk & 1023;     // window within image
  const int wr   = wIdx >> 5;
  const int wc   = wIdx & 31;

  // ---------------- phase 0: stage x -> Xb (bf16), rpb -> RPB ----------------
  {
    const int h0 = wr * 8 + 4;     // shifted->original coord offset (+shift, mod 256)
    const int w0 = wc * 8 + 4;
    #pragma unroll
    for (int i = 0; i < 48; i++) {
      int idx = i * 256 + tid;         // 0..12287 ; c = idx>>6 (const per wave), t = lane
      int c = idx >> 6, t = idx & 63;
      int hh = (h0 + (t >> 3)) & 255;
      int ww = (w0 + (t & 7)) & 255;
      float v = x[(((size_t)(b * 192 + c)) << 16) + (hh << 8) + ww];
      Xb[t * 200 + c] = f2bfu(v);
    }
    for (int i = tid; i < 1800; i += 256)
      RPB[(i & 7) * 228 + (i >> 3)] = rpb[i];   // rpb[idx*8+h] -> RPB[h][idx]
  }
  __syncthreads();

  // ---------------- phase 1: QKV^T = Wqkv(576x192) @ X^T ----------------
  {
    short8 bx[4][6];   // whole X tile in registers: B[k=c][n=t]
    #pragma unroll
    for (int tt = 0; tt < 4; tt++)
      #pragma unroll
      for (int kk = 0; kk < 6; kk++)
        bx[tt][kk] = *(const short8*)(Xb + (tt * 16 + n16) * 200 + kk * 32 + q4 * 8);

    #pragma unroll 1
    for (int ot9 = 0; ot9 < 9; ot9++) {
      const int obase = (wave * 9 + ot9) * 16;    // 0..560
      f32x4 acc[4] = {{0,0,0,0},{0,0,0,0},{0,0,0,0},{0,0,0,0}};
      #pragma unroll
      for (int kk = 0; kk < 6; kk++) {
        const float* wp = qkv_w + (size_t)(obase + n16) * 192 + kk * 32 + q4 * 8;
        f32x4 w0 = *(const f32x4*)wp;
        f32x4 w1 = *(const f32x4*)(wp + 4);
        short8 af;
        af[0]=f2bfu(w0[0]); af[1]=f2bfu(w0[1]); af[2]=f2bfu(w0[2]); af[3]=f2bfu(w0[3]);
        af[4]=f2bfu(w1[0]); af[5]=f2bfu(w1[1]); af[6]=f2bfu(w1[2]); af[7]=f2bfu(w1[3]);
        #pragma unroll
        for (int tt = 0; tt < 4; tt++)
          acc[tt] = __builtin_amdgcn_mfma_f32_16x16x32_bf16(af, bx[tt][kk], acc[tt], 0, 0, 0);
      }
      // route D[o][t] to Qs/Ks/Vt (sec uniform per 16-tile since 192%16==0)
      const int sec = obase / 192;
      #pragma unroll
      for (int r = 0; r < 4; r++) {
        const int o = obase + q4 * 4 + r;
        const float bias = qkv_b[o];
        const int rem = o - sec * 192;       // h*24 + ch, packed 0..191
        #pragma unroll
        for (int tt = 0; tt < 4; tt++) {
          const int t = tt * 16 + n16;
          unsigned short hv = f2bfu(acc[tt][r] + bias);
          if (sec == 0)      Qs[t * 200 + rem] = hv;
          else if (sec == 1) Ks[t * 200 + rem] = hv;
          else               Vt[rem * 72 + t] = hv;
        }
      }
    }
  }
  __syncthreads();

  // ---------------- phase 2: attention; wave handles heads {wave, wave+4} ----------------
  {
    unsigned short* Pw = lds + SCR_OFF + wave * 4608;   // per-wave P buffer [64][72]
    const float scale = 0.20412414523193154f;           // 24^-0.5
    const short8 zero8 = {0,0,0,0,0,0,0,0};

    #pragma unroll 1
    for (int hi = 0; hi < 2; hi++) {
      const int h = wave + hi * 4;

      // S = Q_h @ K_h^T  (K-dim 24 padded to 32: q4==3 quad zeroed)
      short8 qa[4], kb[4];
      #pragma unroll
      for (int i = 0; i < 4; i++) {
        if (q4 < 3) {
          qa[i] = *(const short8*)(Qs + (i * 16 + n16) * 200 + h * 24 + q4 * 8);
          kb[i] = *(const short8*)(Ks + (i * 16 + n16) * 200 + h * 24 + q4 * 8);
        } else { qa[i] = zero8; kb[i] = zero8; }
      }
      f32x4 s[4][4];
      #pragma unroll
      for (int mi = 0; mi < 4; mi++)
        #pragma unroll
        for (int nj = 0; nj < 4; nj++) {
          f32x4 z = {0,0,0,0};
          s[mi][nj] = __builtin_amdgcn_mfma_f32_16x16x32_bf16(qa[mi], kb[nj], z, 0, 0, 0);
        }

      // bias + mask + rowwise softmax (row spread over 16 lanes of the quad x 4 nj)
      const float* rh = RPB + h * 228;
      int cr[4], cc[4], clab[4];
      #pragma unroll
      for (int nj = 0; nj < 4; nj++) {
        int col = nj * 16 + n16;
        cr[nj] = col >> 3; cc[nj] = col & 7;
        int hs = wr * 8 + cr[nj], wsc = wc * 8 + cc[nj];
        int lh = (hs < 248) ? 0 : (hs < 252 ? 1 : 2);
        int lw = (wsc < 248) ? 0 : (wsc < 252 ? 1 : 2);
        clab[nj] = lh * 3 + lw;
      }
      #pragma unroll
      for (int mi = 0; mi < 4; mi++) {
        #pragma unroll
        for (int r = 0; r < 4; r++) {
          int row = mi * 16 + q4 * 4 + r;
          int r1 = row >> 3, c1 = row & 7;
          int hs = wr * 8 + r1, wsc = wc * 8 + c1;
          int lh = (hs < 248) ? 0 : (hs < 252 ? 1 : 2);
          int lw = (wsc < 248) ? 0 : (wsc < 252 ? 1 : 2);
          int rlab = lh * 3 + lw;
          float vals[4];
          float mx = -1e30f;
          #pragma unroll
          for (int nj = 0; nj < 4; nj++) {
            float v = s[mi][nj][r] * scale
                    + rh[(r1 - cr[nj] + 7) * 15 + (c1 - cc[nj] + 7)]
                    + ((rlab == clab[nj]) ? 0.0f : -100.0f);
            vals[nj] = v;
            mx = fmaxf(mx, v);
          }
          mx = fmaxf(mx, __shfl_xor(mx, 1));
          mx = fmaxf(mx, __shfl_xor(mx, 2));
          mx = fmaxf(mx, __shfl_xor(mx, 4));
          mx = fmaxf(mx, __shfl_xor(mx, 8));
          float sum = 0.f;
          #pragma unroll
          for (int nj = 0; nj < 4; nj++) { float p = __expf(vals[nj] - mx); vals[nj] = p; sum += p; }
          sum += __shfl_xor(sum, 1);
          sum += __shfl_xor(sum, 2);
          sum += __shfl_xor(sum, 4);
          sum += __shfl_xor(sum, 8);
          float inv = 1.0f / sum;
          #pragma unroll
          for (int nj = 0; nj < 4; nj++)
            Pw[row * 72 + nj * 16 + n16] = f2bfu(vals[nj] * inv);
        }
      }

      // O_h = P @ V_h  (N=24 padded to 32: cols>=24 discarded)
      short8 vb[2][2];
      #pragma unroll
      for (int nc = 0; nc < 2; nc++)
        #pragma unroll
        for (int kk = 0; kk < 2; kk++)
          vb[nc][kk] = *(const short8*)(Vt + (h * 24 + nc * 16 + n16) * 72 + kk * 32 + q4 * 8);
      #pragma unroll
      for (int mi = 0; mi < 4; mi++) {
        short8 pa0 = *(const short8*)(Pw + (mi * 16 + n16) * 72 + q4 * 8);
        short8 pa1 = *(const short8*)(Pw + (mi * 16 + n16) * 72 + 32 + q4 * 8);
        #pragma unroll
        for (int nc = 0; nc < 2; nc++) {
          f32x4 a = {0,0,0,0};
          a = __builtin_amdgcn_mfma_f32_16x16x32_bf16(pa0, vb[nc][0], a, 0, 0, 0);
          a = __builtin_amdgcn_mfma_f32_16x16x32_bf16(pa1, vb[nc][1], a, 0, 0, 0);
          const int ch = nc * 16 + n16;
          if (ch < 24) {
            #pragma unroll
            for (int r = 0; r < 4; r++) {
              const int t = mi * 16 + q4 * 4 + r;
              Os[t * 200 + h * 24 + ch] = f2bfu(a[r]);
            }
          }
        }
      }
    }
  }
  __syncthreads();

  // ---------------- phase 3: proj^T = Pw(192x192) @ O^T, + residual ----------------
  {
    short8 bo[4][6];
    #pragma unroll
    for (int tt = 0; tt < 4; tt++)
      #pragma unroll
      for (int kk = 0; kk < 6; kk++)
        bo[tt][kk] = *(const short8*)(Os + (tt * 16 + n16) * 200 + kk * 32 + q4 * 8);

    #pragma unroll 1
    for (int ot3 = 0; ot3 < 3; ot3++) {
      const int obase = (wave * 3 + ot3) * 16;
      f32x4 acc[4] = {{0,0,0,0},{0,0,0,0},{0,0,0,0},{0,0,0,0}};
      #pragma unroll
      for (int kk = 0; kk < 6; kk++) {
        const float* wp = proj_w + (size_t)(obase + n16) * 192 + kk * 32 + q4 * 8;
        f32x4 w0 = *(const f32x4*)wp;
        f32x4 w1 = *(const f32x4*)(wp + 4);
        short8 af;
        af[0]=f2bfu(w0[0]); af[1]=f2bfu(w0[1]); af[2]=f2bfu(w0[2]); af[3]=f2bfu(w0[3]);
        af[4]=f2bfu(w1[0]); af[5]=f2bfu(w1[1]); af[6]=f2bfu(w1[2]); af[7]=f2bfu(w1[3]);
        #pragma unroll
        for (int tt = 0; tt < 4; tt++)
          acc[tt] = __builtin_amdgcn_mfma_f32_16x16x32_bf16(af, bo[tt][kk], acc[tt], 0, 0, 0);
      }
      // D[o][t]: 16 lanes = 16 consecutive tokens -> two 8-wide coalesced runs
      #pragma unroll
      for (int r = 0; r < 4; r++) {
        const int o = obase + q4 * 4 + r;
        const float pb = proj_b[o];
        const size_t cbase = ((size_t)(b * 192 + o)) << 16;
        #pragma unroll
        for (int tt = 0; tt < 4; tt++) {
          const int t = tt * 16 + n16;
          const int hh = (wr * 8 + (t >> 3) + 4) & 255;
          const int ww = (wc * 8 + (t & 7) + 4) & 255;
          const size_t gi = cbase + (hh << 8) + ww;
          out[gi] = x[gi] + acc[tt][r] + pb;
        }
      }
    }
  }
}

extern "C" void kernel_launch(void* const* d_in, const int* in_sizes, int n_in,
                              void* d_out, int out_size, void* d_ws, size_t ws_size,
                              hipStream_t stream) {
  const float* x      = (const float*)d_in[0];
  const float* qkv_w  = (const float*)d_in[1];
  const float* qkv_b  = (const float*)d_in[2];
  const float* proj_w = (const float*)d_in[3];
  const float* proj_b = (const float*)d_in[4];
  const float* rpb    = (const float*)d_in[5];
  float* out = (float*)d_out;

  // opt-in to >64KB dynamic LDS (idempotent, host-side: graph-capture safe)
  hipFuncSetAttribute(reinterpret_cast<const void*>(&winattn_kernel),
                      hipFuncAttributeMaxDynamicSharedMemorySize, LDS_BYTES);

  winattn_kernel<<<dim3(4096), dim3(256), LDS_BYTES, stream>>>(
      x, qkv_w, qkv_b, proj_w, proj_b, rpb, out);
}

// Round 2
// 772.886 us; speedup vs baseline: 1.7885x; 1.7885x over previous
//
#include <hip/hip_runtime.h>

// Swin shifted-window attention, fused. B=4, C=192, H=W=256, ws=8, shift=4,
// heads=8, hd=24, N=64. 1 block = 1 window, 512 threads = 8 waves.
// Weights are pre-converted to bf16 and fragment-swizzled into d_ws by a
// prologue kernel, so phase1/3 A-frag loads are single coalesced short8 loads.
//
// MFMA 16x16x32 bf16 layouts (learn_hip-verified):
//   A-frag: lane holds A[m=lane&15][k=(lane>>4)*8 + j]
//   B-frag: lane holds B[k=(lane>>4)*8 + j][n=lane&15]
//   C/D   : lane holds D[row=(lane>>4)*4 + r][col=lane&15]

typedef short short8 __attribute__((ext_vector_type(8)));
typedef float f32x4 __attribute__((ext_vector_type(4)));
typedef unsigned short us4 __attribute__((ext_vector_type(4)));

// LDS layout (offsets in 16-bit units unless noted)
#define XB_OFF   0        // [64][200] bf16 staged x, token-major; residual source
#define QS_OFF   12800    // [64][200] bf16 Q token-major;  reused as Os in phase 2b/3
#define OS_OFF   12800
#define KS_OFF   25600    // [64][200] bf16 K token-major
#define VT_OFF   38400    // [200][72] bf16 V channel-major (rows 192..199 slack)
#define PB_OFF   52800    // [8 waves][16][72] bf16 P tile scratch
#define RPB_BYTE 124032   // float [8][228] rpb head-major
#define BS_BYTE  131328   // float [768] biases: qkv_b(576) ++ proj_b(192)
#define LDS_BYTES 134400

__device__ __forceinline__ unsigned short f2bfu(float f) {
  union { float f; unsigned u; } v; v.f = f;
  unsigned u = v.u;
  u += 0x7fffu + ((u >> 16) & 1u);   // round-to-nearest-even
  return (unsigned short)(u >> 16);
}
__device__ __forceinline__ float bfu2f(unsigned short s) {
  union { unsigned u; float f; } v; v.u = ((unsigned)s) << 16;
  return v.f;
}

// -------- prologue: qkv_w/proj_w -> bf16, fragment-swizzled into ws --------
// dst[((tile*6 + kk)*64 + lane)*8 + j] = W[(tile16 + (lane&15))*192 + kk*32 + (lane>>4)*8 + j]
// tiles 0..35 = qkv rows 0..575 ; tiles 36..47 = proj rows 0..191
__global__ void prep_weights(const float* __restrict__ qkv_w,
                             const float* __restrict__ proj_w,
                             unsigned short* __restrict__ wbf) {
  int d = blockIdx.x * 512 + threadIdx.x;     // 0..147455
  int j    = d & 7;
  int lane = (d >> 3) & 63;
  int kk   = (d >> 9) % 6;
  int tile = d / 3072;
  int n16 = lane & 15, q4 = lane >> 4;
  int col = kk * 32 + q4 * 8 + j;
  float v = (tile < 36) ? qkv_w[(tile * 16 + n16) * 192 + col]
                        : proj_w[((tile - 36) * 16 + n16) * 192 + col];
  wbf[d] = f2bfu(v);
}

__global__ __launch_bounds__(512, 2) void winattn_kernel(
    const float* __restrict__ x, const float* __restrict__ qkv_b,
    const float* __restrict__ proj_b, const float* __restrict__ rpb,
    const unsigned short* __restrict__ wbf, float* __restrict__ out)
{
  extern __shared__ __align__(16) char smem[];
  unsigned short* lds = (unsigned short*)smem;
  float* RPB = (float*)(smem + RPB_BYTE);
  float* Bs  = (float*)(smem + BS_BYTE);

  const int tid  = threadIdx.x;
  const int lane = tid & 63;
  const int wave = tid >> 6;      // 0..7
  const int n16  = lane & 15;
  const int q4   = lane >> 4;

  // XCD-aware swizzle: assume xcd = blk & 7; give each XCD a contiguous run of
  // window columns so adjacent windows (which share 64B x/out lines) stay in
  // one L2. Perf heuristic only.
  const int blk = blockIdx.x;
  const int L   = (blk & 7) * 512 + (blk >> 3);   // 0..4095 logical
  const int b    = L >> 10;
  const int wIdx = L & 1023;
  const int wr   = wIdx >> 5;
  const int wc   = wIdx & 31;

  // ---------------- phase 0: stage x (bf16), rpb, biases ----------------
  {
    const int trow = wave;               // token row 0..7
    const int c3 = lane >> 3, w3 = lane & 7;
    const int hh  = (wr * 8 + 4 + trow) & 255;
    const int ww  = (wc * 8 + 4 + w3) & 255;
    const int t   = trow * 8 + w3;
    #pragma unroll
    for (int it = 0; it < 12; it++) {
      const int c = it * 16 + c3 * 2;
      const float* xp = x + (((size_t)(b * 192 + c)) << 16) + (hh << 8) + ww;
      float v0 = xp[0];
      float v1 = xp[65536];
      unsigned pk = (unsigned)f2bfu(v0) | ((unsigned)f2bfu(v1) << 16);
      *(unsigned*)(lds + XB_OFF + t * 200 + c) = pk;
    }
    for (int i = tid; i < 1800; i += 512)
      RPB[(i & 7) * 228 + (i >> 3)] = rpb[i];      // rpb[idx*8+h] -> RPB[h][idx]
    for (int i = tid; i < 768; i += 512)
      Bs[i] = (i < 576) ? qkv_b[i] : proj_b[i - 576];
  }
  __syncthreads();

  // ---------------- phase 1: QKV^T = Wqkv(576x192) @ X^T ----------------
  {
    short8 bx[4][6];
    #pragma unroll
    for (int tt = 0; tt < 4; tt++)
      #pragma unroll
      for (int kk = 0; kk < 6; kk++)
        bx[tt][kk] = *(const short8*)(lds + XB_OFF + (tt * 16 + n16) * 200 + kk * 32 + q4 * 8);

    #pragma unroll 1
    for (int ot = wave; ot < 36; ot += 8) {
      f32x4 acc[4] = {{0,0,0,0},{0,0,0,0},{0,0,0,0},{0,0,0,0}};
      #pragma unroll
      for (int kk = 0; kk < 6; kk++) {
        short8 af = *(const short8*)(wbf + (ot * 6 + kk) * 512 + lane * 8);
        #pragma unroll
        for (int tt = 0; tt < 4; tt++)
          acc[tt] = __builtin_amdgcn_mfma_f32_16x16x32_bf16(af, bx[tt][kk], acc[tt], 0, 0, 0);
      }
      const int sec  = ot / 12;
      const int remb = (ot % 12) * 16 + q4 * 4;
      const int ob   = ot * 16 + q4 * 4;
      const float b0 = Bs[ob], b1 = Bs[ob + 1], b2 = Bs[ob + 2], b3 = Bs[ob + 3];
      if (sec < 2) {
        unsigned short* dst = lds + (sec == 0 ? QS_OFF : KS_OFF);
        #pragma unroll
        for (int tt = 0; tt < 4; tt++) {
          const int t = tt * 16 + n16;
          us4 hv = { f2bfu(acc[tt][0] + b0), f2bfu(acc[tt][1] + b1),
                     f2bfu(acc[tt][2] + b2), f2bfu(acc[tt][3] + b3) };
          *(us4*)(dst + t * 200 + remb) = hv;
        }
      } else {
        #pragma unroll
        for (int tt = 0; tt < 4; tt++) {
          const int t = tt * 16 + n16;
          lds[VT_OFF + (remb + 0) * 72 + t] = f2bfu(acc[tt][0] + b0);
          lds[VT_OFF + (remb + 1) * 72 + t] = f2bfu(acc[tt][1] + b1);
          lds[VT_OFF + (remb + 2) * 72 + t] = f2bfu(acc[tt][2] + b2);
          lds[VT_OFF + (remb + 3) * 72 + t] = f2bfu(acc[tt][3] + b3);
        }
      }
    }
  }
  __syncthreads();

  // ---------------- phase 2: attention; wave = head ----------------
  {
    const int h = wave;
    const float scale = 0.20412414523193154f;   // 24^-0.5
    const short8 zero8 = {0,0,0,0,0,0,0,0};

    // 2a: load Q/K fragments and V (Qs/Ks dead after this + barrier)
    short8 qa[4], kb[4];
    #pragma unroll
    for (int i = 0; i < 4; i++) {
      if (q4 < 3) {
        qa[i] = *(const short8*)(lds + QS_OFF + (i * 16 + n16) * 200 + h * 24 + q4 * 8);
        kb[i] = *(const short8*)(lds + KS_OFF + (i * 16 + n16) * 200 + h * 24 + q4 * 8);
      } else { qa[i] = zero8; kb[i] = zero8; }
    }
    f32x4 s[4][4];
    #pragma unroll
    for (int mi = 0; mi < 4; mi++)
      #pragma unroll
      for (int nj = 0; nj < 4; nj++) {
        f32x4 z = {0,0,0,0};
        s[mi][nj] = __builtin_amdgcn_mfma_f32_16x16x32_bf16(qa[mi], kb[nj], z, 0, 0, 0);
      }
    short8 vb[2][2];
    #pragma unroll
    for (int nc = 0; nc < 2; nc++)
      #pragma unroll
      for (int kk = 0; kk < 2; kk++)
        vb[nc][kk] = *(const short8*)(lds + VT_OFF + (h * 24 + nc * 16 + n16) * 72 + kk * 32 + q4 * 8);
    __syncthreads();   // all Qs/Ks reads done; Os (=Qs) writable below

    // 2b: softmax + PV, streamed per 16-row tile
    unsigned short* Pw = lds + PB_OFF + wave * 1152;   // [16][72]
    const float* rh = RPB + h * 228;
    int cr[4], cc[4], clab[4];
    #pragma unroll
    for (int nj = 0; nj < 4; nj++) {
      int col = nj * 16 + n16;
      cr[nj] = col >> 3; cc[nj] = col & 7;
      int hs = wr * 8 + cr[nj], wsc = wc * 8 + cc[nj];
      int lh = (hs < 248) ? 0 : (hs < 252 ? 1 : 2);
      int lw = (wsc < 248) ? 0 : (wsc < 252 ? 1 : 2);
      clab[nj] = lh * 3 + lw;
    }
    #pragma unroll 1
    for (int mi = 0; mi < 4; mi++) {
      #pragma unroll
      for (int r = 0; r < 4; r++) {
        int row = mi * 16 + q4 * 4 + r;
        int r1 = row >> 3, c1 = row & 7;
        int hs = wr * 8 + r1, wsc = wc * 8 + c1;
        int lh = (hs < 248) ? 0 : (hs < 252 ? 1 : 2);
        int lw = (wsc < 248) ? 0 : (wsc < 252 ? 1 : 2);
        int rlab = lh * 3 + lw;
        float vals[4];
        float mx = -1e30f;
        #pragma unroll
        for (int nj = 0; nj < 4; nj++) {
          float v = s[mi][nj][r] * scale
                  + rh[(r1 - cr[nj] + 7) * 15 + (c1 - cc[nj] + 7)]
                  + ((rlab == clab[nj]) ? 0.0f : -100.0f);
          vals[nj] = v;
          mx = fmaxf(mx, v);
        }
        mx = fmaxf(mx, __shfl_xor(mx, 1));
        mx = fmaxf(mx, __shfl_xor(mx, 2));
        mx = fmaxf(mx, __shfl_xor(mx, 4));
        mx = fmaxf(mx, __shfl_xor(mx, 8));
        float sum = 0.f;
        #pragma unroll
        for (int nj = 0; nj < 4; nj++) { float p = __expf(vals[nj] - mx); vals[nj] = p; sum += p; }
        sum += __shfl_xor(sum, 1);
        sum += __shfl_xor(sum, 2);
        sum += __shfl_xor(sum, 4);
        sum += __shfl_xor(sum, 8);
        float inv = 1.0f / sum;
        #pragma unroll
        for (int nj = 0; nj < 4; nj++)
          Pw[(q4 * 4 + r) * 72 + nj * 16 + n16] = f2bfu(vals[nj] * inv);
      }
      short8 pa0 = *(const short8*)(Pw + n16 * 72 + q4 * 8);
      short8 pa1 = *(const short8*)(Pw + n16 * 72 + 32 + q4 * 8);
      #pragma unroll
      for (int nc = 0; nc < 2; nc++) {
        f32x4 a = {0,0,0,0};
        a = __builtin_amdgcn_mfma_f32_16x16x32_bf16(pa0, vb[nc][0], a, 0, 0, 0);
        a = __builtin_amdgcn_mfma_f32_16x16x32_bf16(pa1, vb[nc][1], a, 0, 0, 0);
        const int ch = nc * 16 + n16;
        if (ch < 24) {
          #pragma unroll
          for (int r = 0; r < 4; r++) {
            const int t = mi * 16 + q4 * 4 + r;
            lds[OS_OFF + t * 200 + h * 24 + ch] = f2bfu(a[r]);
          }
        }
      }
    }
  }
  __syncthreads();

  // ---------------- phase 3: proj^T = Wp(192x192) @ O^T, + residual ----------------
  {
    short8 bo[4][6];
    #pragma unroll
    for (int tt = 0; tt < 4; tt++)
      #pragma unroll
      for (int kk = 0; kk < 6; kk++)
        bo[tt][kk] = *(const short8*)(lds + OS_OFF + (tt * 16 + n16) * 200 + kk * 32 + q4 * 8);

    #pragma unroll 1
    for (int ot = wave; ot < 12; ot += 8) {
      f32x4 acc[4] = {{0,0,0,0},{0,0,0,0},{0,0,0,0},{0,0,0,0}};
      #pragma unroll
      for (int kk = 0; kk < 6; kk++) {
        short8 af = *(const short8*)(wbf + ((36 + ot) * 6 + kk) * 512 + lane * 8);
        #pragma unroll
        for (int tt = 0; tt < 4; tt++)
          acc[tt] = __builtin_amdgcn_mfma_f32_16x16x32_bf16(af, bo[tt][kk], acc[tt], 0, 0, 0);
      }
      #pragma unroll
      for (int r = 0; r < 4; r++) {
        const int o = ot * 16 + q4 * 4 + r;
        const float pb = Bs[576 + o];
        const size_t cbase = ((size_t)(b * 192 + o)) << 16;
        #pragma unroll
        for (int tt = 0; tt < 4; tt++) {
          const int t = tt * 16 + n16;
          const int hh = (wr * 8 + (t >> 3) + 4) & 255;
          const int ww = (wc * 8 + (t & 7) + 4) & 255;
          out[cbase + (hh << 8) + ww] = bfu2f(lds[XB_OFF + t * 200 + o]) + acc[tt][r] + pb;
        }
      }
    }
  }
}

extern "C" void kernel_launch(void* const* d_in, const int* in_sizes, int n_in,
                              void* d_out, int out_size, void* d_ws, size_t ws_size,
                              hipStream_t stream) {
  const float* x      = (const float*)d_in[0];
  const float* qkv_w  = (const float*)d_in[1];
  const float* qkv_b  = (const float*)d_in[2];
  const float* proj_w = (const float*)d_in[3];
  const float* proj_b = (const float*)d_in[4];
  const float* rpb    = (const float*)d_in[5];
  float* out = (float*)d_out;
  unsigned short* wbf = (unsigned short*)d_ws;    // 147456 shorts = 294912 B

  hipFuncSetAttribute(reinterpret_cast<const void*>(&winattn_kernel),
                      hipFuncAttributeMaxDynamicSharedMemorySize, LDS_BYTES);

  prep_weights<<<dim3(288), dim3(512), 0, stream>>>(qkv_w, proj_w, wbf);
  winattn_kernel<<<dim3(4096), dim3(512), LDS_BYTES, stream>>>(
      x, qkv_b, proj_b, rpb, wbf, out);
}